// Round 22
// baseline (4604.922 us; speedup 1.0000x reference)
//
#include <hip/hip_runtime.h>

// T=512, B=64, D=1024, H=2048, L=256
// d_out (f32): recon[65536] | recon_seq[512*64*1024] | latent_seq[512*64*256] | spike_rate[3] | recon_err[1]
//
// Round 22: ref = JAX/XLA-CPU outputs (stored as np): GEMM K-block 512
// (enc [512,512], lat/rec [512x4], dec [256] -- r15's partition, the only
// one within a single flip of ref) + fast-math-contracted LIF:
//   V = fma(0.9f, V, I)  (ONE rounding), s=(V-1>0), V-=s.
// This is the unique untested cell of (partition x LIF-rounding); all prior
// failures (r15 2-round LIF; r17/r19/r21 fold-deltas; r20 wrong partitions)
// are consistent with one hair-trigger dec site flipped by ANY deviation.

#define T_STEPS 512
#define BB 64
#define DD 1024
#define HH 2048
#define LL 256
#define KC_PANEL 512   // fixed stride, remainder last

// ---------------------------------------------------------------------------
// Panel GEMM, fixed-KC remainder-last partition: C[M,N](f32) = A@B + bias.
// A float or uchar(0/1). 128x64 tile, BK=16, 256 threads, 8x4 per thread.
// M%128==0, N%64==0, K%16==0 (KC_PANEL=512=32*16).
// ---------------------------------------------------------------------------
template<typename AT>
__global__ __launch_bounds__(256) void gemm_panel(
    const AT* __restrict__ A, const float* __restrict__ Bm,
    const float* __restrict__ bias, float* __restrict__ C,
    int M, int N, int K)
{
  __shared__ float As[16][128];
  __shared__ float Bs[16][64];
  const int tid = threadIdx.x;
  const int tx = tid & 15, ty = tid >> 4;
  const int row0 = blockIdx.y * 128, col0 = blockIdx.x * 64;
  const int ar = tid >> 1;                    // A row 0..127
  const int ak = (tid & 1) * 8;               // A k-offset 0/8
  const int br = tid >> 4;                    // B k-row 0..15
  const int bn = (tid & 15) * 4;              // B col 0..60

  float acc[8][4] = {};    // folded panels
  float pacc[8][4] = {};   // current panel (ascending-k FMA chain)
  const int KT = K >> 4;
  for (int kt = 0; kt < KT; ++kt) {
    if (kt > 0 && ((kt * 16) % KC_PANEL) == 0) {   // panel boundary: fold
      #pragma unroll
      for (int i = 0; i < 8; ++i)
        #pragma unroll
        for (int j = 0; j < 4; ++j) {
          acc[i][j] = __fadd_rn(acc[i][j], pacc[i][j]);
          pacc[i][j] = 0.0f;
        }
    }
    // stage tile
    float a[8];
    if constexpr (sizeof(AT) == 1) {
      unsigned long long w =
          *(const unsigned long long*)(A + (size_t)(row0 + ar) * K + kt * 16 + ak);
      #pragma unroll
      for (int j = 0; j < 8; ++j) a[j] = (float)((w >> (8 * j)) & 0xFFull);
    } else {
      const float* ap = (const float*)A + (size_t)(row0 + ar) * K + kt * 16 + ak;
      float4 f0 = *(const float4*)ap;
      float4 f1 = *(const float4*)(ap + 4);
      a[0] = f0.x; a[1] = f0.y; a[2] = f0.z; a[3] = f0.w;
      a[4] = f1.x; a[5] = f1.y; a[6] = f1.z; a[7] = f1.w;
    }
    float4 bf = *(const float4*)(Bm + (size_t)(kt * 16 + br) * N + col0 + bn);
    __syncthreads();                 // previous tile's compute done
    #pragma unroll
    for (int j = 0; j < 8; ++j) As[ak + j][ar] = a[j];
    Bs[br][bn + 0] = bf.x; Bs[br][bn + 1] = bf.y;
    Bs[br][bn + 2] = bf.z; Bs[br][bn + 3] = bf.w;
    __syncthreads();
    #pragma unroll
    for (int k = 0; k < 16; ++k) {   // global k ascending within panel
      float av[8], bv[4];
      #pragma unroll
      for (int i = 0; i < 8; ++i) av[i] = As[k][ty * 8 + i];
      #pragma unroll
      for (int j = 0; j < 4; ++j) bv[j] = Bs[k][tx * 4 + j];
      #pragma unroll
      for (int i = 0; i < 8; ++i)
        #pragma unroll
        for (int j = 0; j < 4; ++j)
          pacc[i][j] = fmaf(av[i], bv[j], pacc[i][j]);
    }
  }
  #pragma unroll
  for (int i = 0; i < 8; ++i)
    #pragma unroll
    for (int j = 0; j < 4; ++j) {
      float tot = __fadd_rn(acc[i][j], pacc[i][j]);          // final fold
      tot = __fadd_rn(tot, bias[col0 + tx * 4 + j]);         // "+ b" (b==0)
      C[(size_t)(row0 + ty * 8 + i) * N + col0 + tx * 4 + j] = tot;
    }
}

// ---------------------------------------------------------------------------
// Elementwise LIF scan: v = fma(0.9f, v, I) (XLA fast-math contraction);
// s = (v-1>0); v -= s. Spike bytes, optional f32 latent, per-wave count.
// ---------------------------------------------------------------------------
__global__ __launch_bounds__(256) void lif_scan(
    const float* __restrict__ I, float* __restrict__ V,
    unsigned char* __restrict__ S, float* __restrict__ latent,
    unsigned long long* __restrict__ cnt, int Tc, int NTOT)
{
  const int idx = blockIdx.x * 256 + threadIdx.x;
  float v = V[idx];
  unsigned c = 0;
  for (int t = 0; t < Tc; ++t) {
    v = fmaf(0.9f, v, I[(size_t)t * NTOT + idx]);   // single rounding
    const bool s = __fsub_rn(v, 1.0f) > 0.0f;
    if (s) v = __fsub_rn(v, 1.0f);
    S[(size_t)t * NTOT + idx] = (unsigned char)s;
    if (latent) latent[(size_t)t * NTOT + idx] = s ? 1.0f : 0.0f;
    c += (unsigned)s;
  }
  V[idx] = v;
  unsigned long long cc = c;
  for (int o = 32; o; o >>= 1) cc += __shfl_down(cc, o);
  if ((threadIdx.x & 63) == 0 && cc) atomicAdd(cnt, cc);
}

// ---------------------------------------------------------------------------
__global__ __launch_bounds__(256) void recon_mean_kernel(
    const float* __restrict__ rs, float* __restrict__ out)
{
  const int idx = blockIdx.x * 256 + threadIdx.x;   // 65536 total
  double s = 0.0;
  for (int t = 0; t < T_STEPS; ++t) s += (double)rs[(size_t)t * 65536 + idx];
  out[idx] = (float)(s * (1.0 / 512.0));
}

__global__ __launch_bounds__(256) void err_kernel(
    const float* __restrict__ rs, const float* __restrict__ x,
    double* __restrict__ acc)
{
  const size_t N = (size_t)T_STEPS * BB * DD;
  double s = 0.0;
  for (size_t i = (size_t)blockIdx.x * 256 + threadIdx.x; i < N;
       i += (size_t)gridDim.x * 256)
    s += (double)fabsf(rs[i] - x[i]);
  for (int o = 32; o; o >>= 1) s += __shfl_down(s, o);
  __shared__ double wsum[4];
  if ((threadIdx.x & 63) == 0) wsum[threadIdx.x >> 6] = s;
  __syncthreads();
  if (threadIdx.x == 0) atomicAdd(acc, wsum[0] + wsum[1] + wsum[2] + wsum[3]);
}

__global__ void finalize_kernel(const double* __restrict__ acc,
                                const unsigned long long* __restrict__ cnt,
                                float* __restrict__ sr, float* __restrict__ err)
{
  if (threadIdx.x == 0) {
    sr[0] = (float)((double)cnt[0] / (512.0 * 64.0 * 2048.0));
    sr[1] = (float)((double)cnt[1] / (512.0 * 64.0 * 256.0));
    sr[2] = (float)((double)cnt[2] / (512.0 * 64.0 * 2048.0));
    err[0] = (float)(acc[0] / (512.0 * 64.0 * 1024.0));
  }
}

// ---------------------------------------------------------------------------
extern "C" void kernel_launch(void* const* d_in, const int* in_sizes, int n_in,
                              void* d_out, int out_size, void* d_ws, size_t ws_size,
                              hipStream_t stream) {
  const float* x    = (const float*)d_in[0];
  const float* Wenc = (const float*)d_in[1];
  const float* benc = (const float*)d_in[2];
  const float* Wlat = (const float*)d_in[3];
  const float* blat = (const float*)d_in[4];
  const float* Wdec = (const float*)d_in[5];
  const float* bdec = (const float*)d_in[6];
  const float* Wrec = (const float*)d_in[7];
  const float* brec = (const float*)d_in[8];

  float* out = (float*)d_out;
  float* recon     = out;
  float* recon_seq = out + 65536;
  float* latent    = recon_seq + (size_t)T_STEPS * BB * DD;
  float* sr        = latent + (size_t)T_STEPS * BB * LL;
  float* errp      = sr + 3;

  char* ws = (char*)d_ws;
  float* Ve = (float*)ws;                                   // 512 KB
  float* Vl = (float*)(ws + 524288);                        // 64 KB
  float* Vd = (float*)(ws + 589824);                        // 512 KB
  unsigned long long* cnt = (unsigned long long*)(ws + 1114112);  // 24 B
  double* errAcc = (double*)(ws + 1114136);                 // 8 B
  const size_t STATE = 1114368;

  unsigned char* Senc = (unsigned char*)(ws + STATE);       // 64 MB (Sdec overlaid)
  unsigned char* Sdec = Senc;
  const size_t Z_OFF    = STATE + 67108864;
  unsigned char* Z      = (unsigned char*)(ws + Z_OFF);     // 8 MB
  const size_t ILAT_OFF = Z_OFF + 8388608;
  float* Ilat           = (float*)(ws + ILAT_OFF);          // 32 MB
  const size_t ICH_OFF  = ILAT_OFF + 33554432;
  float* Ichunk         = (float*)(ws + ICH_OFF);           // Tc*512 KB

  int Tc = 512;
  while (Tc > 2 && ICH_OFF + (size_t)Tc * 524288 > ws_size) Tc >>= 1;

  hipMemsetAsync(ws, 0, STATE, stream);

  // Stage 1+2: encoder GEMM (folds [512,512]) + Ve scan (FMA-LIF)
  for (int c0 = 0; c0 < T_STEPS; c0 += Tc) {
    gemm_panel<float><<<dim3(HH / 64, Tc * BB / 128), 256, 0, stream>>>(
        x + (size_t)c0 * BB * DD, Wenc, benc, Ichunk, Tc * BB, HH, DD);
    lif_scan<<<512, 256, 0, stream>>>(
        Ichunk, Ve, Senc + (size_t)c0 * BB * HH, nullptr, &cnt[0], Tc, BB * HH);
  }
  // Stage 3+4: latent GEMM (binary A, folds [512x4]) + Vl scan, whole T
  gemm_panel<unsigned char><<<dim3(LL / 64, T_STEPS * BB / 128), 256, 0, stream>>>(
      Senc, Wlat, blat, Ilat, T_STEPS * BB, LL, HH);
  lif_scan<<<64, 256, 0, stream>>>(
      Ilat, Vl, Z, latent, &cnt[1], T_STEPS, BB * LL);
  // Stage 5+6+7: decoder GEMM (K=256 single panel) + Vd scan + recon GEMM
  for (int c0 = 0; c0 < T_STEPS; c0 += Tc) {
    gemm_panel<unsigned char><<<dim3(HH / 64, Tc * BB / 128), 256, 0, stream>>>(
        Z + (size_t)c0 * BB * LL, Wdec, bdec, Ichunk, Tc * BB, HH, LL);
    lif_scan<<<512, 256, 0, stream>>>(
        Ichunk, Vd, Sdec + (size_t)c0 * BB * HH, nullptr, &cnt[2], Tc, BB * HH);
    gemm_panel<unsigned char><<<dim3(DD / 64, Tc * BB / 128), 256, 0, stream>>>(
        Sdec + (size_t)c0 * BB * HH, Wrec, brec,
        recon_seq + (size_t)c0 * BB * DD, Tc * BB, DD, HH);
  }

  recon_mean_kernel<<<256, 256, 0, stream>>>(recon_seq, recon);
  err_kernel<<<2048, 256, 0, stream>>>(recon_seq, x, errAcc);
  finalize_kernel<<<1, 64, 0, stream>>>(errAcc, cnt, sr, errp);
}